// Round 3
// baseline (193.835 us; speedup 1.0000x reference)
//
#include <hip/hip_runtime.h>
#include <hip/hip_bf16.h>
#include <stdint.h>

typedef __attribute__((ext_vector_type(8))) short bf16x8;
typedef __attribute__((ext_vector_type(4))) short short4v;
typedef __attribute__((ext_vector_type(4))) float f32x4;

#define LDS3(p) ((__attribute__((address_space(3))) void*)(p))
#define GLB1(p) ((const __attribute__((address_space(1))) void*)(p))

constexpr int Bc = 4;
constexpr int Cc = 256;   // channels (= d_v)
constexpr int Nn = 4096;  // H*W
constexpr int Dq = 32;    // C/8 (= d_qk)
constexpr float L2E = 1.4426950408889634f;

__device__ __forceinline__ short f2b(float x) {
  union { float f; uint32_t u; } v; v.f = x;
  uint32_t r = (v.u + 0x7fffu + ((v.u >> 16) & 1u)) >> 16;  // RNE
  return (short)(r & 0xffffu);
}

// ---------------------------------------------------------------------------
// Kernel 1: transpose-convert f1/f2 [B][C][N] f32 -> [B][N][C] bf16
// ---------------------------------------------------------------------------
__global__ __launch_bounds__(256) void prep_transpose(
    const float* __restrict__ f1, const float* __restrict__ f2,
    short* __restrict__ f1T, short* __restrict__ f2T) {
  __shared__ float tile[64][65];
  const int bx = blockIdx.x;
  const int which = bx >> 10;          // 0: f1, 1: f2
  const int rem = bx & 1023;
  const int b = rem >> 8;
  const int cb = (rem >> 6) & 3;
  const int nb = rem & 63;
  const float* src = which ? f2 : f1;
  short* dst = which ? f2T : f1T;
  const int c0 = cb * 64, n0 = nb * 64;
  const int tid = threadIdx.x;
  const int lane = tid & 63;
  const int row4 = tid >> 6;
#pragma unroll
  for (int i = 0; i < 16; ++i) {
    const int cl = row4 + i * 4;
    tile[cl][lane] = src[(size_t)(b * Cc + c0 + cl) * Nn + n0 + lane];
  }
  __syncthreads();
#pragma unroll
  for (int i = 0; i < 16; ++i) {
    const int nl = row4 + i * 4;
    dst[(size_t)(b * Nn + n0 + nl) * Cc + c0 + lane] = f2b(tile[lane][nl]);
  }
}

// ---------------------------------------------------------------------------
// Kernel 2: convert weights f32 -> bf16 (layouts preserved: [out][in])
// ---------------------------------------------------------------------------
__global__ __launch_bounds__(256) void prep_weights(
    const float* __restrict__ Wq, const float* __restrict__ Wk,
    const float* __restrict__ Wv, short* __restrict__ Wq_b,
    short* __restrict__ Wk_b, short* __restrict__ Wv_b) {
  const int base = (blockIdx.x * 256 + threadIdx.x) * 4;
#pragma unroll
  for (int j = 0; j < 4; ++j) {
    const int idx = base + j;
    if (idx < 8192) Wq_b[idx] = f2b(Wq[idx]);
    else if (idx < 16384) Wk_b[idx - 8192] = f2b(Wk[idx - 8192]);
    else if (idx < 16384 + 65536) Wv_b[idx - 16384] = f2b(Wv[idx - 16384]);
  }
}

// ---------------------------------------------------------------------------
// Kernel 3: projections via MFMA (unchanged, known-good).
// ---------------------------------------------------------------------------
__global__ __launch_bounds__(256) void proj_qkv(
    const short* __restrict__ f1T, const short* __restrict__ f2T,
    const short* __restrict__ Wq_b, const float* __restrict__ bq,
    const short* __restrict__ Wk_b, const float* __restrict__ bk,
    const short* __restrict__ Wv_b, const float* __restrict__ bv,
    short* __restrict__ q_ws, short* __restrict__ k_ws,
    short* __restrict__ v_ws) {
  const int bx = blockIdx.x;
  const int b = bx >> 6;
  const int n0 = (bx & 63) * 64;
  const int tid = threadIdx.x;
  const int w = tid >> 6;
  const int lane = tid & 63;
  const int l16 = lane & 15;
  const int g = lane >> 4;

#pragma unroll
  for (int qk = 0; qk < 2; ++qk) {
    const short* X = qk ? f2T : f1T;
    const short* Wm = qk ? Wk_b : Wq_b;
    const float* bias_p = qk ? bk : bq;
    short* outp = qk ? k_ws : q_ws;
    f32x4 accq[2] = {(f32x4){0.f, 0.f, 0.f, 0.f}, (f32x4){0.f, 0.f, 0.f, 0.f}};
#pragma unroll
    for (int kc = 0; kc < 8; ++kc) {
      const bf16x8 a = *(const bf16x8*)&X[(size_t)(b * Nn + n0 + w * 16 + l16) * Cc + kc * 32 + g * 8];
#pragma unroll
      for (int ob = 0; ob < 2; ++ob) {
        const bf16x8 bb = *(const bf16x8*)&Wm[(ob * 16 + l16) * Cc + kc * 32 + g * 8];
        accq[ob] = __builtin_amdgcn_mfma_f32_16x16x32_bf16(a, bb, accq[ob], 0, 0, 0);
      }
    }
#pragma unroll
    for (int ob = 0; ob < 2; ++ob) {
      const float bias = bias_p[ob * 16 + l16];
#pragma unroll
      for (int r = 0; r < 4; ++r) {
        const int n = n0 + w * 16 + g * 4 + r;
        outp[(size_t)(b * Nn + n) * Dq + ob * 16 + l16] = f2b(accq[ob][r] + bias);
      }
    }
  }

  {
    f32x4 acc[4][4];
#pragma unroll
    for (int ci = 0; ci < 4; ++ci)
#pragma unroll
      for (int nb = 0; nb < 4; ++nb) acc[ci][nb] = (f32x4){0.f, 0.f, 0.f, 0.f};
#pragma unroll
    for (int kc = 0; kc < 8; ++kc) {
      bf16x8 bfr[4];
#pragma unroll
      for (int nb = 0; nb < 4; ++nb)
        bfr[nb] = *(const bf16x8*)&f2T[(size_t)(b * Nn + n0 + nb * 16 + l16) * Cc + kc * 32 + g * 8];
#pragma unroll
      for (int ci = 0; ci < 4; ++ci) {
        const bf16x8 afr = *(const bf16x8*)&Wv_b[((w * 4 + ci) * 16 + l16) * Cc + kc * 32 + g * 8];
#pragma unroll
        for (int nb = 0; nb < 4; ++nb)
          acc[ci][nb] = __builtin_amdgcn_mfma_f32_16x16x32_bf16(afr, bfr[nb], acc[ci][nb], 0, 0, 0);
      }
    }
#pragma unroll
    for (int ci = 0; ci < 4; ++ci) {
#pragma unroll
      for (int r = 0; r < 4; ++r) {
        const int c = (w * 4 + ci) * 16 + g * 4 + r;
        const float bias = bv[c];
#pragma unroll
        for (int nb = 0; nb < 4; ++nb) {
          const int n = n0 + nb * 16 + l16;
          v_ws[(size_t)(b * Cc + c) * Nn + n] = f2b(acc[ci][nb][r] + bias);
        }
      }
    }
  }
}

// ---------------------------------------------------------------------------
// Kernel 4: flash attention v3 — 8 waves (512 thr), wave = 32 rows x 64 ch.
// 2 waves/SIMD for latency hiding; V LDS reads halved (each frag feeds 2 mb).
// Softmax wave-local (c-split waves recompute it; no cross-wave coupling).
// V double-buffered via global_load_lds (linear dest / pre-swizzled source /
// swizzled read). Defer-max THR=8. One barrier per 64-key tile.
// XCD-bijective block swizzle: each XCD works one batch's contiguous range.
// ---------------------------------------------------------------------------
constexpr int NT = 64;
constexpr int NTILES = Nn / NT;        // 64
constexpr int VBUF = 256 * NT * 2;     // 32768 B per buffer ([c][8 granules])
constexpr int POFF = 2 * VBUF;         // 65536
constexpr int PSTRIDE = 4096;          // per-wave P strip: 32 rows x 128 B
constexpr int SBYTES = POFF + 8 * PSTRIDE;  // 98304

__global__ __launch_bounds__(512) void attn_kernel(
    const short* __restrict__ q_ws, const short* __restrict__ k_ws,
    const short* __restrict__ v_ws, const float* __restrict__ feat1,
    const float* __restrict__ gamma_p, float* __restrict__ out) {
  __shared__ __align__(16) char smem[SBYTES];
  const int bx = blockIdx.x;
  const int swz = (bx & 7) * 32 + (bx >> 3);  // XCD-contiguous (256 = 8*32)
  const int b = swz >> 6;
  const int m0 = (swz & 63) * 64;
  const int tid = threadIdx.x;
  const int w = tid >> 6;     // 0..7
  const int rg = w >> 2;      // row group: rows [rg*32, rg*32+32)
  const int cg = w & 3;       // channel group: [cg*64, cg*64+64)
  const int lane = tid & 63;
  const int l16 = lane & 15;
  const int g = lane >> 4;

  // Q frags (B operand): rows m = m0 + rg*32 + mb*16 + l16, k = g*8+j
  bf16x8 qfrag[2];
#pragma unroll
  for (int mb = 0; mb < 2; ++mb)
    qfrag[mb] = *(const bf16x8*)&q_ws[(size_t)(b * Nn + m0 + rg * 32 + mb * 16 + l16) * Dq + g * 8];

  // V stage: 2048 granules of 16B = [256 c][8 key-slots]; 4 per thread.
  // Source pre-swizzled (slot ^= c&7) so linear LDS-DMA lands swizzled image.
  const int cth = tid >> 3;
  const int s7 = tid & 7;
  const short* vsrc[4];
#pragma unroll
  for (int j = 0; j < 4; ++j) {
    const int c = j * 64 + cth;
    vsrc[j] = v_ws + (size_t)(b * Cc + c) * Nn + 8 * (s7 ^ (c & 7));
  }

  const short* kptr = k_ws + (size_t)(b * Nn + l16) * Dq + g * 8;

  f32x4 acc[2][4];  // O[m = rg*32 + mb*16 + 4g+r][c = cg*64 + cb*16 + l16]
#pragma unroll
  for (int mb = 0; mb < 2; ++mb)
#pragma unroll
    for (int cb = 0; cb < 4; ++cb) acc[mb][cb] = (f32x4){0.f, 0.f, 0.f, 0.f};

  float mrun[2] = {-INFINITY, -INFINITY};
  float lrun[2] = {0.f, 0.f};

  // prologue: stage tile 0, prefetch K(0)
#pragma unroll
  for (int j = 0; j < 4; ++j) {
    char* ldst = &smem[(j * 512 + w * 64) * 16];
    __builtin_amdgcn_global_load_lds(GLB1(vsrc[j]), LDS3(ldst), 16, 0, 0);
    vsrc[j] += NT;
  }
  bf16x8 kf[4];
#pragma unroll
  for (int nb = 0; nb < 4; ++nb)
    kf[nb] = *(const bf16x8*)(kptr + nb * 16 * Dq);
  kptr += NT * Dq;

  const int pb = POFF + w * PSTRIDE;
  const int psw = l16 & 7;

  for (int t = 0; t < NTILES; ++t) {
    const int buf = t & 1;
    // ---- S^T = K*Q^T: lane holds S[m][n = t*64 + nb*16 + 4g + r]
    f32x4 s[2][4];
#pragma unroll
    for (int mb = 0; mb < 2; ++mb)
#pragma unroll
      for (int nb = 0; nb < 4; ++nb)
        s[mb][nb] = __builtin_amdgcn_mfma_f32_16x16x32_bf16(
            kf[nb], qfrag[mb], (f32x4){0.f, 0.f, 0.f, 0.f}, 0, 0, 0);

    // ---- wave-local online softmax (rows l16 of each mb half)
    float tmax[2];
#pragma unroll
    for (int mb = 0; mb < 2; ++mb) {
      float tm = fmaxf(fmaxf(s[mb][0][0], s[mb][0][1]), fmaxf(s[mb][0][2], s[mb][0][3]));
#pragma unroll
      for (int nb = 1; nb < 4; ++nb)
        tm = fmaxf(tm, fmaxf(fmaxf(s[mb][nb][0], s[mb][nb][1]),
                             fmaxf(s[mb][nb][2], s[mb][nb][3])));
      tm = fmaxf(tm, __shfl_xor(tm, 16));
      tm = fmaxf(tm, __shfl_xor(tm, 32));
      tmax[mb] = tm;
    }
    if (__any((tmax[0] > mrun[0] + 8.f) || (tmax[1] > mrun[1] + 8.f))) {
#pragma unroll
      for (int mb = 0; mb < 2; ++mb) {
        const float mnew = fmaxf(mrun[mb], tmax[mb]);
        const float scl = exp2f((mrun[mb] - mnew) * L2E);
        float sc[4];
#pragma unroll
        for (int r = 0; r < 4; ++r) sc[r] = __shfl(scl, (g << 2) | r);
#pragma unroll
        for (int cb = 0; cb < 4; ++cb)
#pragma unroll
          for (int r = 0; r < 4; ++r) acc[mb][cb][r] *= sc[r];
        lrun[mb] *= scl;
        mrun[mb] = mnew;
      }
    }
#pragma unroll
    for (int mb = 0; mb < 2; ++mb) {
      float psum = 0.f;
      short4v pk[4];
#pragma unroll
      for (int nb = 0; nb < 4; ++nb)
#pragma unroll
        for (int r = 0; r < 4; ++r) {
          const float p = exp2f((s[mb][nb][r] - mrun[mb]) * L2E);
          psum += p;
          pk[nb][r] = f2b(p);
        }
      psum += __shfl_xor(psum, 16);
      psum += __shfl_xor(psum, 32);
      lrun[mb] += psum;
      // P write (wave-private, swizzled 16B granules; 8B per nb)
#pragma unroll
      for (int nb = 0; nb < 4; ++nb) {
        const int off = (((nb * 2 + (g >> 1)) ^ psw) << 4) | ((g & 1) << 3);
        *(short4v*)&smem[pb + mb * 2048 + l16 * 128 + off] = pk[nb];
      }
    }

    asm volatile("s_waitcnt vmcnt(0)" ::: "memory");  // own V(t) parts done
    __syncthreads();                                   // all parts visible

    if (t + 1 < NTILES) {
#pragma unroll
      for (int j = 0; j < 4; ++j) {
        char* ldst = &smem[(buf ^ 1) * VBUF + (j * 512 + w * 64) * 16];
        __builtin_amdgcn_global_load_lds(GLB1(vsrc[j]), LDS3(ldst), 16, 0, 0);
        vsrc[j] += NT;
      }
#pragma unroll
      for (int nb = 0; nb < 4; ++nb)
        kf[nb] = *(const bf16x8*)(kptr + nb * 16 * Dq);
      kptr += NT * Dq;
    }

    // ---- PV: A = P[mb half][keys], B = V[keys][this wave's 64 channels]
#pragma unroll
    for (int kk = 0; kk < 2; ++kk) {
      bf16x8 pA[2];
#pragma unroll
      for (int mb = 0; mb < 2; ++mb)
        pA[mb] = *(const bf16x8*)&smem[pb + mb * 2048 + l16 * 128 +
                                       (((kk * 4 + g) ^ psw) << 4)];
#pragma unroll
      for (int cb = 0; cb < 4; ++cb) {
        const int c = cg * 64 + cb * 16 + l16;
        const bf16x8 vB = *(const bf16x8*)&smem[buf * VBUF +
            (c * 8 + ((kk * 4 + g) ^ (c & 7))) * 16];
#pragma unroll
        for (int mb = 0; mb < 2; ++mb)
          acc[mb][cb] = __builtin_amdgcn_mfma_f32_16x16x32_bf16(pA[mb], vB, acc[mb][cb], 0, 0, 0);
      }
    }
  }

  // ---- epilogue: per-wave transpose via LDS, out = gamma*O/l + feat1
  __syncthreads();  // done with V/P regions; reuse for transpose
  float inv[2][4];
#pragma unroll
  for (int mb = 0; mb < 2; ++mb)
#pragma unroll
    for (int r = 0; r < 4; ++r)
      inv[mb][r] = 1.f / __shfl(lrun[mb], (g << 2) | r);
  float* ow = (float*)&smem[w * 8448];  // [64 c][33 m] f32, wave-private
#pragma unroll
  for (int mb = 0; mb < 2; ++mb)
#pragma unroll
    for (int cb = 0; cb < 4; ++cb)
#pragma unroll
      for (int r = 0; r < 4; ++r)
        ow[(cb * 16 + l16) * 33 + mb * 16 + 4 * g + r] = acc[mb][cb][r] * inv[mb][r];
  asm volatile("s_waitcnt lgkmcnt(0)" ::: "memory");  // wave-local write->read
  const float gam = gamma_p[0];
  const int mm = lane & 31;
  const int c2 = lane >> 5;
  const size_t obase = (size_t)b * Cc * Nn + (size_t)(m0 + rg * 32 + mm);
#pragma unroll 8
  for (int cc = 0; cc < 32; ++cc) {
    const int c_local = cc * 2 + c2;
    const int c = cg * 64 + c_local;
    const size_t oi = obase + (size_t)c * Nn;
    out[oi] = gam * ow[c_local * 33 + mm] + feat1[oi];
  }
}

// ---------------------------------------------------------------------------
// Launch
// ---------------------------------------------------------------------------
extern "C" void kernel_launch(void* const* d_in, const int* in_sizes, int n_in,
                              void* d_out, int out_size, void* d_ws,
                              size_t ws_size, hipStream_t stream) {
  const float* feat1 = (const float*)d_in[0];
  const float* feat2 = (const float*)d_in[1];
  const float* Wq = (const float*)d_in[2];
  const float* bq = (const float*)d_in[3];
  const float* Wk = (const float*)d_in[4];
  const float* bk = (const float*)d_in[5];
  const float* Wv = (const float*)d_in[6];
  const float* bv = (const float*)d_in[7];
  const float* gamma = (const float*)d_in[8];
  float* out = (float*)d_out;

  char* ws = (char*)d_ws;
  short* f1T = (short*)(ws + 0);           //  8 MiB
  short* f2T = (short*)(ws + 8388608);     //  8 MiB
  short* q_ws = (short*)(ws + 16777216);   //  1 MiB
  short* k_ws = (short*)(ws + 17825792);   //  1 MiB
  short* v_ws = (short*)(ws + 18874368);   //  8 MiB
  short* Wq_b = (short*)(ws + 27262976);   // 16 KiB
  short* Wk_b = (short*)(ws + 27279360);   // 16 KiB
  short* Wv_b = (short*)(ws + 27295744);   // 128 KiB

  prep_transpose<<<2048, 256, 0, stream>>>(feat1, feat2, f1T, f2T);
  prep_weights<<<80, 256, 0, stream>>>(Wq, Wk, Wv, Wq_b, Wk_b, Wv_b);
  proj_qkv<<<256, 256, 0, stream>>>(f1T, f2T, Wq_b, bq, Wk_b, bk, Wv_b, bv,
                                    q_ws, k_ws, v_ws);
  attn_kernel<<<256, 512, 0, stream>>>(q_ws, k_ws, v_ws, feat1, gamma, out);
}